// Round 5
// baseline (71.432 us; speedup 1.0000x reference)
//
#include <hip/hip_runtime.h>

#define TPB 512
#define RPB 16                          // rows per tile
#define SEQ_L 2048
#define CHUNK 512                       // j-chunk width = TPB
#define NCH (SEQ_L / CHUNK)             // 4
#define NBATCH 8
#define NBLOCKS 256                     // 1 per CU; 8 batches x 32 blocks
#define NWAVE (TPB / 64)

static constexpr float kBondTol  = 0.4f;
static constexpr float kClashTol = 1.5f;
static constexpr float kIdeal    = 3.8f;
static constexpr float kEps      = 1e-8f;
static constexpr float kThresh2  = 2.25f;   // 1.5^2: d2 >= this -> relu == 0

__device__ __forceinline__ float wred(float v) {
#pragma unroll
  for (int o = 32; o > 0; o >>= 1) v += __shfl_down(v, o, 64);
  return v;
}

__global__ __launch_bounds__(TPB, 2) void viol_main(
    const float* __restrict__ pos,    // [B, L, 3]
    const float* __restrict__ mask,   // [B, L]
    float4* __restrict__ partial) {   // [NBLOCKS]: (bv, bm, 2*cv_half, pm)
  __shared__ float4 s[SEQ_L];         // x, y, z, mask  (32 KB)
  __shared__ float  redm[NWAVE];
  __shared__ float  red4[NWAVE][4];

  // batch = low 3 bits -> same batch pinned to one XCD's L2
  const int b = blockIdx.x & 7;
  const int r = blockIdx.x >> 3;      // 0..31
  // 4 tiles per block; triangular work sums are constant across r:
  // work(t) ~ (128 - t); (r)+(127-r)+(63-r)+(64+r) = 254 for all r.
  int tiles[4];
  tiles[0] = r; tiles[1] = 127 - r; tiles[2] = 63 - r; tiles[3] = 64 + r;

  const float* pb = pos  + (size_t)b * SEQ_L * 3;
  const float* mb = mask + (size_t)b * SEQ_L;

  // ---- stage batch into LDS once, accumulate mask-sum on the side ----
  float mpart = 0.f;
#pragma unroll
  for (int it = 0; it < SEQ_L / TPB; ++it) {
    int idx = threadIdx.x + it * TPB;
    float x = pb[3 * idx + 0];
    float y = pb[3 * idx + 1];
    float z = pb[3 * idx + 2];
    float m = mb[idx];
    s[idx] = make_float4(x, y, z, m);
    mpart += m;
  }
  mpart = wred(mpart);
  const int wid  = threadIdx.x >> 6;
  const int lane = threadIdx.x & 63;
  if (lane == 0) redm[wid] = mpart;
  __syncthreads();
  float msum = 0.f;
#pragma unroll
  for (int w = 0; w < NWAVE; ++w) msum += redm[w];

  float cv = 0.f, pm = 0.f, bv = 0.f, bm = 0.f;

  // ---- process 4 tiles against the staged batch (strict upper triangle) ----
  for (int tt = 0; tt < 4; ++tt) {
    const int i0 = tiles[tt] << 4;

    float px[RPB], py[RPB], pz[RPB], pw[RPB], accr[RPB];
#pragma unroll
    for (int q = 0; q < RPB; ++q) {
      float4 p = s[i0 + q];           // broadcast read (conflict-free)
      px[q] = p.x; py[q] = p.y; pz[q] = p.z; pw[q] = p.w;
      accr[q] = 0.f;
    }

    const int k0 = i0 >> 9;           // 512-chunk containing this tile

    // boundary chunk (contains the diagonal): masked, always-sqrt
    {
      const int j = threadIdx.x + (k0 << 9);
      const float4 pj = s[j];
#pragma unroll
      for (int q = 0; q < RPB; ++q) {
        const int i = i0 + q;
        float dx = pj.x - px[q];
        float dy = pj.y - py[q];
        float dz = pj.z - pz[q];
        float d2 = fmaf(dx, dx, fmaf(dy, dy, dz * dz));
        float dist = __builtin_amdgcn_sqrtf(d2 + kEps);
        float mw = (j > i) ? pj.w : 0.f;        // strict upper triangle
        accr[q] = fmaf(fmaxf(kClashTol - dist, 0.f), mw, accr[q]);
      }
    }

    // full chunks above the tile: d2-only + wave-uniform sqrt skip
#pragma unroll 2
    for (int k = k0 + 1; k < NCH; ++k) {
      float4 pj = s[threadIdx.x + (k << 9)];
      float d2r[RPB];
#pragma unroll
      for (int q = 0; q < RPB; ++q) {
        float dx = pj.x - px[q];
        float dy = pj.y - py[q];
        float dz = pj.z - pz[q];
        d2r[q] = fmaf(dx, dx, fmaf(dy, dy, dz * dz));
      }
      float mv = d2r[0];
#pragma unroll
      for (int q = 1; q < RPB; ++q) mv = fminf(mv, d2r[q]);  // fuses to min3
      if (__ballot(mv < kThresh2) != 0ull) {
#pragma unroll
        for (int q = 0; q < RPB; ++q) {
          float dist = __builtin_amdgcn_sqrtf(d2r[q] + kEps);
          accr[q] = fmaf(fmaxf(kClashTol - dist, 0.f), pj.w, accr[q]);
        }
      }
    }

#pragma unroll
    for (int q = 0; q < RPB; ++q) cv = fmaf(pw[q], accr[q], cv);
  }

  // ---- near-diagonal correction (i < j <= i+2) + bond + analytic pm ----
  // 64 rows per block (4 tiles x 16): one full wave handles them.
  if (threadIdx.x < 64) {
    const int tile = tiles[threadIdx.x >> 4];
    const int i = (tile << 4) + (threadIdx.x & 15);
    const float4 pi = s[i];
    float nv = 0.f;
    const int jhi = (i + 2 > SEQ_L - 1) ? SEQ_L - 1 : i + 2;
    for (int j = i + 1; j <= jhi; ++j) {
      float4 pj = s[j];
      float dx = pj.x - pi.x;
      float dy = pj.y - pi.y;
      float dz = pj.z - pi.z;
      float dist = __builtin_amdgcn_sqrtf(dx * dx + dy * dy + dz * dz + kEps);
      nv += fmaxf(kClashTol - dist, 0.f) * pj.w;
    }
    cv -= pi.w * nv;                  // remove strict-upper near-diagonal

    float nm = 0.f;                   // full |i-j|<=2 window incl. j==i
    const int jlo = (i - 2 < 0) ? 0 : i - 2;
    for (int j = jlo; j <= jhi; ++j) nm += s[j].w;
    pm += pi.w * (msum - nm);         // analytic pair-mask row sum

    if (i < SEQ_L - 1) {
      const float4 pj = s[i + 1];
      float dx = pj.x - pi.x;
      float dy = pj.y - pi.y;
      float dz = pj.z - pi.z;
      float dist = __builtin_amdgcn_sqrtf(dx * dx + dy * dy + dz * dz + kEps);
      float viol = fmaxf(fabsf(dist - kIdeal) - kBondTol, 0.f);
      bv += viol * pi.w * pj.w;
      bm += pi.w * pj.w;
    }
  }

  // ---- block reduction -> ONE plain float4 store per block (no atomics) ----
  bv = wred(bv); bm = wred(bm); cv = wred(cv); pm = wred(pm);
  if (lane == 0) {
    red4[wid][0] = bv; red4[wid][1] = bm;
    red4[wid][2] = cv; red4[wid][3] = pm;
  }
  __syncthreads();
  if (threadIdx.x == 0) {
    float tbv = 0.f, tbm = 0.f, tcv = 0.f, tpm = 0.f;
#pragma unroll
    for (int w = 0; w < NWAVE; ++w) {
      tbv += red4[w][0]; tbm += red4[w][1];
      tcv += red4[w][2]; tpm += red4[w][3];
    }
    // x2: upper triangle -> full ordered sum
    partial[blockIdx.x] = make_float4(tbv, tbm, 2.f * tcv, tpm);
  }
}

__global__ __launch_bounds__(256) void viol_reduce(
    const float4* __restrict__ partial, float* __restrict__ out) {
  __shared__ float red4[4][4];
  float4 p = partial[threadIdx.x];    // 256 partials, one per thread
  float bv = wred(p.x), bm = wred(p.y), cv = wred(p.z), pm = wred(p.w);
  const int wid  = threadIdx.x >> 6;
  const int lane = threadIdx.x & 63;
  if (lane == 0) {
    red4[wid][0] = bv; red4[wid][1] = bm;
    red4[wid][2] = cv; red4[wid][3] = pm;
  }
  __syncthreads();
  if (threadIdx.x == 0) {
    float tbv = 0.f, tbm = 0.f, tcv = 0.f, tpm = 0.f;
#pragma unroll
    for (int w = 0; w < 4; ++w) {
      tbv += red4[w][0]; tbm += red4[w][1];
      tcv += red4[w][2]; tpm += red4[w][3];
    }
    float bond  = tbv / (tbm + kEps);
    float clash = tcv / (tpm + kEps);
    out[0] = bond;
    out[1] = clash;
    out[2] = bond + clash;
  }
}

extern "C" void kernel_launch(void* const* d_in, const int* in_sizes, int n_in,
                              void* d_out, int out_size, void* d_ws, size_t ws_size,
                              hipStream_t stream) {
  const float* pos  = (const float*)d_in[0];
  const float* mask = (const float*)d_in[1];
  float* out = (float*)d_out;
  float4* partial = (float4*)d_ws;   // 256 * 16 B = 4 KB scratch

  viol_main<<<dim3(NBLOCKS), dim3(TPB), 0, stream>>>(pos, mask, partial);
  viol_reduce<<<dim3(1), dim3(256), 0, stream>>>(partial, out);
}

// Round 6
// 64.995 us; speedup vs baseline: 1.0990x; 1.0990x over previous
//
#include <hip/hip_runtime.h>

#define TPB 256
#define RPB 16                         // rows per block (register tile)
#define SEQ_L 2048
#define JPT (SEQ_L / TPB)              // 256-wide j-chunks = 8
#define NBATCH 8
#define NBLOCKS (NBATCH * (SEQ_L / RPB))   // 1024

static constexpr float kBondTol  = 0.4f;
static constexpr float kClashTol = 1.5f;
static constexpr float kIdeal    = 3.8f;
static constexpr float kEps      = 1e-8f;
static constexpr float kThresh2  = 2.25f;   // 1.5^2: d2 >= this -> relu == 0

__device__ __forceinline__ float wred(float v) {
#pragma unroll
  for (int o = 32; o > 0; o >>= 1) v += __shfl_down(v, o, 64);
  return v;
}

__global__ __launch_bounds__(TPB, 4) void viol_main(
    const float* __restrict__ pos,    // [B, L, 3]
    const float* __restrict__ mask,   // [B, L]
    float4* __restrict__ partial) {   // [NBLOCKS]: (bv, bm, 2*cv_half, pm)
  __shared__ float4 s[SEQ_L];         // x, y, z, mask  (32 KB; [jbase,2048) valid)
  __shared__ float  redm[TPB / 64];
  __shared__ float  red4[TPB / 64][4];

  // ---- balanced tile permutation for the triangular workload ----
  // Group {2r, 127-2r, 2r+1, 126-2r}: constant Sum(work) AND ~constant
  // Sum(staging iters) for any stride-256 block sample on a CU.
  const int u = blockIdx.x >> 3;
  const int b = blockIdx.x & 7;
  const int v = u >> 5, rr = u & 31;
  int tile;
  if      (v == 0) tile = 2 * rr;
  else if (v == 1) tile = 127 - 2 * rr;
  else if (v == 2) tile = 2 * rr + 1;
  else             tile = 126 - 2 * rr;
  const int i0 = tile << 4;
  const int k0 = i0 >> 8;             // first 256-chunk this tile touches
  const int jbase = k0 << 8;

  const float* pb = pos  + (size_t)b * SEQ_L * 3;
  const float* mb = mask + (size_t)b * SEQ_L;

  // ---- full-batch mask sum from global (L2-hit), no LDS needed ----
  float mpart = 0.f;
#pragma unroll
  for (int it = 0; it < JPT; ++it) mpart += mb[threadIdx.x + (it << 8)];
  mpart = wred(mpart);

  // ---- triangular staging: only j in [jbase, 2048) is ever read ----
  for (int idx = jbase + (int)threadIdx.x; idx < SEQ_L; idx += TPB) {
    float x = pb[3 * idx + 0];
    float y = pb[3 * idx + 1];
    float z = pb[3 * idx + 2];
    s[idx] = make_float4(x, y, z, mb[idx]);
  }

  const int wid  = threadIdx.x >> 6;
  const int lane = threadIdx.x & 63;
  if (lane == 0) redm[wid] = mpart;
  __syncthreads();                    // staging + msum barrier
  const float msum = redm[0] + redm[1] + redm[2] + redm[3];

  // ---- register tile: 16 rows in registers ----
  float px[RPB], py[RPB], pz[RPB], pw[RPB], accr[RPB];
#pragma unroll
  for (int q = 0; q < RPB; ++q) {
    float4 p = s[i0 + q];             // broadcast read (conflict-free)
    px[q] = p.x; py[q] = p.y; pz[q] = p.z; pw[q] = p.w;
    accr[q] = 0.f;
  }

  // ---- boundary j-chunk (contains the diagonal): masked, always-sqrt ----
  {
    const int j = (int)threadIdx.x + jbase;
    const float4 pj = s[j];
#pragma unroll
    for (int q = 0; q < RPB; ++q) {
      const int i = i0 + q;
      float dx = pj.x - px[q];
      float dy = pj.y - py[q];
      float dz = pj.z - pz[q];
      float d2 = fmaf(dx, dx, fmaf(dy, dy, dz * dz));
      float dist = __builtin_amdgcn_sqrtf(d2 + kEps);
      float mw = (j > i) ? pj.w : 0.f;          // strict upper triangle
      accr[q] = fmaf(fmaxf(kClashTol - dist, 0.f), mw, accr[q]);
    }
  }

  // ---- full j-chunks above the tile: d2-only + wave-uniform sqrt skip ----
#pragma unroll 2
  for (int k = k0 + 1; k < JPT; ++k) {
    float4 pj = s[threadIdx.x + (k << 8)];
    float d2r[RPB];
#pragma unroll
    for (int q = 0; q < RPB; ++q) {
      float dx = pj.x - px[q];
      float dy = pj.y - py[q];
      float dz = pj.z - pz[q];
      d2r[q] = fmaf(dx, dx, fmaf(dy, dy, dz * dz));
    }
    float mv = d2r[0];
#pragma unroll
    for (int q = 1; q < RPB; ++q) mv = fminf(mv, d2r[q]);   // fuses to min3
    if (__ballot(mv < kThresh2) != 0ull) {
#pragma unroll
      for (int q = 0; q < RPB; ++q) {
        float dist = __builtin_amdgcn_sqrtf(d2r[q] + kEps);
        accr[q] = fmaf(fmaxf(kClashTol - dist, 0.f), pj.w, accr[q]);
      }
    }
  }

  float cv = 0.f, pm = 0.f, bv = 0.f, bm = 0.f;
#pragma unroll
  for (int q = 0; q < RPB; ++q) cv = fmaf(pw[q], accr[q], cv);

  // ---- near-diagonal correction (i < j <= i+2) + bond + analytic pm ----
  if (threadIdx.x < RPB) {
    const int i = i0 + (int)threadIdx.x;
    const float4 pi = s[i];           // i >= i0 >= jbase: staged
    float nv = 0.f;
    const int jhi = (i + 2 > SEQ_L - 1) ? SEQ_L - 1 : i + 2;
    for (int j = i + 1; j <= jhi; ++j) {        // j > i >= jbase: staged
      float4 pj = s[j];
      float dx = pj.x - pi.x;
      float dy = pj.y - pi.y;
      float dz = pj.z - pi.z;
      float dist = __builtin_amdgcn_sqrtf(dx * dx + dy * dy + dz * dz + kEps);
      nv += fmaxf(kClashTol - dist, 0.f) * pj.w;
    }
    cv -= pi.w * nv;

    // nm window may dip below jbase -> read mask from global (L2-hit)
    float nm = 0.f;
    const int jlo = (i - 2 < 0) ? 0 : i - 2;
    for (int j = jlo; j <= jhi; ++j) nm += mb[j];
    pm += pi.w * (msum - nm);         // analytic pair-mask row sum

    if (i < SEQ_L - 1) {
      const float4 pj = s[i + 1];
      float dx = pj.x - pi.x;
      float dy = pj.y - pi.y;
      float dz = pj.z - pi.z;
      float dist = __builtin_amdgcn_sqrtf(dx * dx + dy * dy + dz * dz + kEps);
      float viol = fmaxf(fabsf(dist - kIdeal) - kBondTol, 0.f);
      bv += viol * pi.w * pj.w;
      bm += pi.w * pj.w;
    }
  }

  // ---- block reduction -> ONE plain float4 store per block (no atomics) ----
  bv = wred(bv); bm = wred(bm); cv = wred(cv); pm = wred(pm);
  if (lane == 0) {
    red4[wid][0] = bv; red4[wid][1] = bm;
    red4[wid][2] = cv; red4[wid][3] = pm;
  }
  __syncthreads();
  if (threadIdx.x == 0) {
    float tbv = 0.f, tbm = 0.f, tcv = 0.f, tpm = 0.f;
#pragma unroll
    for (int w = 0; w < TPB / 64; ++w) {
      tbv += red4[w][0]; tbm += red4[w][1];
      tcv += red4[w][2]; tpm += red4[w][3];
    }
    // x2: upper triangle -> full ordered sum
    partial[blockIdx.x] = make_float4(tbv, tbm, 2.f * tcv, tpm);
  }
}

__global__ __launch_bounds__(TPB) void viol_reduce(
    const float4* __restrict__ partial, float* __restrict__ out) {
  __shared__ float red4[TPB / 64][4];
  float bv = 0.f, bm = 0.f, cv = 0.f, pm = 0.f;
#pragma unroll
  for (int i = threadIdx.x; i < NBLOCKS; i += TPB) {
    float4 p = partial[i];
    bv += p.x; bm += p.y; cv += p.z; pm += p.w;
  }
  bv = wred(bv); bm = wred(bm); cv = wred(cv); pm = wred(pm);
  const int wid  = threadIdx.x >> 6;
  const int lane = threadIdx.x & 63;
  if (lane == 0) {
    red4[wid][0] = bv; red4[wid][1] = bm;
    red4[wid][2] = cv; red4[wid][3] = pm;
  }
  __syncthreads();
  if (threadIdx.x == 0) {
    float tbv = 0.f, tbm = 0.f, tcv = 0.f, tpm = 0.f;
#pragma unroll
    for (int w = 0; w < TPB / 64; ++w) {
      tbv += red4[w][0]; tbm += red4[w][1];
      tcv += red4[w][2]; tpm += red4[w][3];
    }
    float bond  = tbv / (tbm + kEps);
    float clash = tcv / (tpm + kEps);
    out[0] = bond;
    out[1] = clash;
    out[2] = bond + clash;
  }
}

extern "C" void kernel_launch(void* const* d_in, const int* in_sizes, int n_in,
                              void* d_out, int out_size, void* d_ws, size_t ws_size,
                              hipStream_t stream) {
  const float* pos  = (const float*)d_in[0];
  const float* mask = (const float*)d_in[1];
  float* out = (float*)d_out;
  float4* partial = (float4*)d_ws;   // 1024 * 16 B = 16 KB scratch

  viol_main<<<dim3(NBLOCKS), dim3(TPB), 0, stream>>>(pos, mask, partial);
  viol_reduce<<<dim3(1), dim3(TPB), 0, stream>>>(partial, out);
}